// Round 4
// baseline (260.376 us; speedup 1.0000x reference)
//
#include <hip/hip_runtime.h>
#include <math.h>

// ---------------------------------------------------------------------------
// GMM log-likelihood, N=2M x D=16, K=32, out = mean_n logsumexp_k loglik[n,k]
//
// loglik[n,k] = sum_{ij} (-0.5 P_ij) x_i x_j + (P mu)_i x_i + c_k  (log2 dom.)
// LINEAR in phi(x) = [ x_i*x_j (256 ordered), x_i (16) ] -> 17 K16-chunks of
// one chained mfma_f32_32x32x16_f16 (M=32 = all comps at once).
// C layout (HW-verified): col=lane&31 (point), row=(reg&3)+8*(reg>>2)+4*(lane>>5).
// Lane pair (l, l^32) holds all 32 comps of a point; combined via
// v_permlane32_swap (VALU-only; R2 showed ds shuffles cost ~62 cyc each).
//
// R4 structure: W lives in LDS (17.4 KB/block, copied once) -> guaranteed
// resident (R2/R3 suspect: VGPR-capped allocator re-loading W per tile from
// global). Freed 68 VGPRs spent on T=2 tiles/iteration: 2 independent MFMA
// accumulator chains (2x ILP), 2x load MLP, each W chunk ds_read once per
// pair. ds addressing lane*16 contiguous -> conflict-free.
// ---------------------------------------------------------------------------

#define LOG_2PI 1.8378770664093453f
#define INV_LN2 1.4426950408889634f
#define LN2_D   0.6931471805599453

typedef float    float4v __attribute__((ext_vector_type(4)));
typedef float    f32x16  __attribute__((ext_vector_type(16)));
typedef _Float16 f16x8   __attribute__((ext_vector_type(8)));
typedef _Float16 f16x2   __attribute__((ext_vector_type(2)));

union H8 { f16x8 h8; f16x2 h2[4]; };

#if __has_builtin(__builtin_amdgcn_exp2f)
#define EXP2F(x) __builtin_amdgcn_exp2f(x)
#else
#define EXP2F(x) exp2f(x)
#endif
#if __has_builtin(__builtin_amdgcn_logf)
#define LOG2F(x) __builtin_amdgcn_logf(x)
#else
#define LOG2F(x) log2f(x)
#endif

static __device__ __forceinline__ f16x2 pk2(float a, float b) {
#if __has_builtin(__builtin_amdgcn_cvt_pkrtz)
  return __builtin_bit_cast(f16x2, __builtin_amdgcn_cvt_pkrtz(a, b));
#else
  f16x2 r; r[0] = (_Float16)a; r[1] = (_Float16)b; return r;
#endif
}

// value of x in partner lane (lane ^ 32), VALU-only on gfx950
static __device__ __forceinline__ float partner32(float x, bool lo) {
#if __has_builtin(__builtin_amdgcn_permlane32_swap)
  typedef unsigned u32x2 __attribute__((ext_vector_type(2)));
  unsigned u = __builtin_bit_cast(unsigned, x);
  u32x2 r = __builtin_amdgcn_permlane32_swap(u, u, false, false);
  return __builtin_bit_cast(float, lo ? r[1] : r[0]);
#else
  return __shfl_xor(x, 32, 64);
#endif
}

// ---------------------------------------------------------------------------
// Setup (unchanged layout): per component k: cov = A A^T, Cholesky L, Linv,
// P = Linv^T Linv.  W in 32x32x16 A-frag order:
// lane l holds A[m=l&31][k16 = 8*(l>>5)+v], chunk c = feature k=16c+8h+v.
// Feature k: [0,256): (i,j)=(k>>4,k&15) -> -0.5/ln2 * P[i][j]
//            [256,272): i=k-256 -> (P mu)_i / ln2.  c2[k] f32 separately.
// ---------------------------------------------------------------------------
__global__ void setup_kernel(const float* __restrict__ means,
                             const float* __restrict__ cov_parts,
                             const float* __restrict__ log_weights,
                             _Float16* __restrict__ W,
                             float* __restrict__ c2)
{
  const int k = blockIdx.x;
  const int i = threadIdx.x;

  __shared__ float sA[16][17];
  __shared__ float sC[16][17];
  __shared__ float sMu[16];
  __shared__ float sR[16];

  if (i < 16) {
    #pragma unroll
    for (int j = 0; j < 16; ++j) sA[i][j] = cov_parts[(k*16 + i)*16 + j];
    sMu[i] = means[k*16 + i];
  }
  __syncthreads();

  if (i < 16) {
    #pragma unroll
    for (int j = 0; j < 16; ++j) {
      float acc = 0.f;
      #pragma unroll
      for (int l = 0; l < 16; ++l) acc += sA[i][l] * sA[j][l];
      sC[i][j] = acc;
    }
  }
  __syncthreads();

  for (int j = 0; j < 16; ++j) {
    if (i == j) {
      float d = sC[j][j];
      for (int l = 0; l < j; ++l) d -= sC[j][l]*sC[j][l];
      sC[j][j] = sqrtf(d);
    }
    __syncthreads();
    if (i < 16 && i > j) {
      float a = sC[i][j];
      for (int l = 0; l < j; ++l) a -= sC[i][l]*sC[j][l];
      sC[i][j] = a / sC[j][j];
    }
    __syncthreads();
  }

  if (i < 16) {
    float y[16];
    #pragma unroll
    for (int r = 0; r < 16; ++r) {
      float a = (r == i) ? 1.f : 0.f;
      #pragma unroll
      for (int l = 0; l < r; ++l) a -= sC[r][l] * y[l];
      y[r] = a / sC[r][r];
    }
    #pragma unroll
    for (int r = 0; r < 16; ++r) sA[r][i] = y[r];
  }
  __syncthreads();

  if (i < 16) {
    float p[16];
    #pragma unroll
    for (int j = 0; j < 16; ++j) {
      float acc = 0.f;
      #pragma unroll
      for (int l = 0; l < 16; ++l) acc += sA[l][i] * sA[l][j];
      p[j] = acc;
    }
    float ri = 0.f;
    #pragma unroll
    for (int j = 0; j < 16; ++j) ri += p[j] * sMu[j];
    sR[i] = ri;

    #pragma unroll
    for (int j = 0; j < 16; ++j) {
      W[(size_t)(i*64 + (k + 32*(j >> 3)))*8 + (j & 7)] =
          (_Float16)(-0.5f * INV_LN2 * p[j]);
    }
    W[(size_t)(16*64 + (k + 32*(i >> 3)))*8 + (i & 7)] =
        (_Float16)(INV_LN2 * ri);
  }
  __syncthreads();

  if (i == 0) {
    float logdet = 0.f;
    #pragma unroll
    for (int j = 0; j < 16; ++j) logdet += __logf(sC[j][j]);
    float mupmu = 0.f;
    #pragma unroll
    for (int j = 0; j < 16; ++j) mupmu += sMu[j] * sR[j];
    float lw = log_weights[k];
    c2[k] = INV_LN2 * (-0.5f*(mupmu + 16.f*LOG_2PI) - logdet + lw*lw);
  }
}

// ---------------------------------------------------------------------------
__global__ __launch_bounds__(256, 3) void main_kernel(
    const float* __restrict__ data,
    const _Float16* __restrict__ W,
    const float* __restrict__ c2,
    float* __restrict__ partials,
    int npts, int ntiles)
{
  __shared__ _Float16 sW[17*64*8];     // 17408 B, one copy per block
  __shared__ float wsum[4];

  // block-cooperative W copy (once)
  {
    const float4v* src = (const float4v*)W;
    float4v* dst = (float4v*)sW;
    for (int idx = threadIdx.x; idx < 17*64*8/8; idx += 256)
      dst[idx] = src[idx];
  }
  __syncthreads();

  const int lane = threadIdx.x & 63;
  const int n32  = lane & 31;
  const bool lo  = lane < 32;
  const int h    = lo ? 0 : 1;
  const int gwave  = (int)((blockIdx.x * blockDim.x + threadIdx.x) >> 6);
  const int nwaves = (int)((gridDim.x * blockDim.x) >> 6);

  const _Float16* sWl = sW + (size_t)lane*8;   // chunk c at +c*512 halfs

  float c2r[16];
  #pragma unroll
  for (int r = 0; r < 16; ++r)
    c2r[r] = c2[(r & 3) + 8*(r >> 2) + 4*h];

  const int npairs = (ntiles + 1) >> 1;
  float accsum = 0.f;

  // prefetch pair gwave
  float4v pA0, pA1, pA2, pA3, pB0, pB1, pB2, pB3;
  if (gwave < npairs) {
    int tA = 2*gwave, tB = (2*gwave+1 < ntiles) ? 2*gwave+1 : 2*gwave;
    const float* xa = data + ((size_t)tA*32 + n32)*16;
    const float* xb = data + ((size_t)tB*32 + n32)*16;
    pA0 = *(const float4v*)(xa);    pA1 = *(const float4v*)(xa + 4);
    pA2 = *(const float4v*)(xa + 8); pA3 = *(const float4v*)(xa + 12);
    pB0 = *(const float4v*)(xb);    pB1 = *(const float4v*)(xb + 4);
    pB2 = *(const float4v*)(xb + 8); pB3 = *(const float4v*)(xb + 12);
  }

  for (int p = gwave; p < npairs; p += nwaves) {
    float xA[16], xB[16];
    #pragma unroll
    for (int j = 0; j < 4; ++j) {
      xA[j] = pA0[j]; xA[4+j] = pA1[j]; xA[8+j] = pA2[j]; xA[12+j] = pA3[j];
      xB[j] = pB0[j]; xB[4+j] = pB1[j]; xB[8+j] = pB2[j]; xB[12+j] = pB3[j];
    }
    const bool validB = (2*p+1 < ntiles);

    int np_ = p + nwaves;
    if (np_ < npairs) {                 // wave-uniform prefetch of next pair
      int tA = 2*np_, tB = (2*np_+1 < ntiles) ? 2*np_+1 : 2*np_;
      const float* xa = data + ((size_t)tA*32 + n32)*16;
      const float* xb = data + ((size_t)tB*32 + n32)*16;
      pA0 = *(const float4v*)(xa);    pA1 = *(const float4v*)(xa + 4);
      pA2 = *(const float4v*)(xa + 8); pA3 = *(const float4v*)(xa + 12);
      pB0 = *(const float4v*)(xb);    pB1 = *(const float4v*)(xb + 4);
      pB2 = *(const float4v*)(xb + 8); pB3 = *(const float4v*)(xb + 12);
    }

    // half-selected second factors (k&15 = 8h + j), once per tile
    f16x2 xsA[4], xsB[4];
    #pragma unroll
    for (int j = 0; j < 4; ++j) {
      unsigned la = __builtin_bit_cast(unsigned, pk2(xA[2*j],   xA[2*j+1]));
      unsigned ha = __builtin_bit_cast(unsigned, pk2(xA[8+2*j], xA[9+2*j]));
      xsA[j] = __builtin_bit_cast(f16x2, lo ? la : ha);
      unsigned lb = __builtin_bit_cast(unsigned, pk2(xB[2*j],   xB[2*j+1]));
      unsigned hb = __builtin_bit_cast(unsigned, pk2(xB[8+2*j], xB[9+2*j]));
      xsB[j] = __builtin_bit_cast(f16x2, lo ? lb : hb);
    }

    f32x16 accA, accB;
    #pragma unroll
    for (int r = 0; r < 16; ++r) { accA[r] = 0.f; accB[r] = 0.f; }

    #pragma unroll
    for (int c = 0; c < 16; ++c) {
      f16x8 wc = *(const f16x8*)(sWl + (size_t)c*512);   // ds_read_b128
      f16x2 xa2 = pk2(xA[c], xA[c]);
      H8 bA;
      #pragma unroll
      for (int j = 0; j < 4; ++j) bA.h2[j] = xa2 * xsA[j];
      accA = __builtin_amdgcn_mfma_f32_32x32x16_f16(wc, bA.h8, accA, 0, 0, 0);
      f16x2 xb2 = pk2(xB[c], xB[c]);
      H8 bB;
      #pragma unroll
      for (int j = 0; j < 4; ++j) bB.h2[j] = xb2 * xsB[j];
      accB = __builtin_amdgcn_mfma_f32_32x32x16_f16(wc, bB.h8, accB, 0, 0, 0);
    }
    {   // linear chunk
      f16x8 wc = *(const f16x8*)(sWl + (size_t)16*512);
      H8 bA, bB;
      #pragma unroll
      for (int j = 0; j < 4; ++j) { bA.h2[j] = xsA[j]; bB.h2[j] = xsB[j]; }
      accA = __builtin_amdgcn_mfma_f32_32x32x16_f16(wc, bA.h8, accA, 0, 0, 0);
      accB = __builtin_amdgcn_mfma_f32_32x32x16_f16(wc, bB.h8, accB, 0, 0, 0);
    }

    // epilogue tile A
    {
      float v[16];
      #pragma unroll
      for (int r = 0; r < 16; ++r) v[r] = accA[r] + c2r[r];
      float m = v[0];
      #pragma unroll
      for (int r = 1; r < 16; ++r) m = fmaxf(m, v[r]);
      m = fmaxf(m, partner32(m, lo));
      float s = 0.f;
      #pragma unroll
      for (int r = 0; r < 16; ++r) s += EXP2F(v[r] - m);
      s += partner32(s, lo);
      accsum += m + LOG2F(s);
    }
    // epilogue tile B
    {
      float v[16];
      #pragma unroll
      for (int r = 0; r < 16; ++r) v[r] = accB[r] + c2r[r];
      float m = v[0];
      #pragma unroll
      for (int r = 1; r < 16; ++r) m = fmaxf(m, v[r]);
      m = fmaxf(m, partner32(m, lo));
      float s = 0.f;
      #pragma unroll
      for (int r = 0; r < 16; ++r) s += EXP2F(v[r] - m);
      s += partner32(s, lo);
      accsum += validB ? (m + LOG2F(s)) : 0.f;
    }
  }

  #pragma unroll
  for (int off = 1; off <= 32; off <<= 1)
    accsum += __shfl_xor(accsum, off, 64);

  const int wid = (int)(threadIdx.x >> 6);
  if ((threadIdx.x & 63) == 0) wsum[wid] = accsum;
  __syncthreads();
  if (threadIdx.x == 0)
    partials[blockIdx.x] = wsum[0] + wsum[1] + wsum[2] + wsum[3];
}

// ---------------------------------------------------------------------------
__global__ void reduce_kernel(const float* __restrict__ partials, int n,
                              float* __restrict__ out, double scale)
{
  __shared__ double sd[256];
  double a = 0.0;
  for (int idx = threadIdx.x; idx < n; idx += 256) a += (double)partials[idx];
  sd[threadIdx.x] = a;
  __syncthreads();
  for (int s = 128; s > 0; s >>= 1) {
    if ((int)threadIdx.x < s) sd[threadIdx.x] += sd[threadIdx.x + s];
    __syncthreads();
  }
  if (threadIdx.x == 0) out[0] = (float)(sd[0] * scale);
}

extern "C" void kernel_launch(void* const* d_in, const int* in_sizes, int n_in,
                              void* d_out, int out_size, void* d_ws, size_t ws_size,
                              hipStream_t stream)
{
  const float* data        = (const float*)d_in[0];
  const float* means       = (const float*)d_in[1];
  const float* cov_parts   = (const float*)d_in[2];
  const float* log_weights = (const float*)d_in[3];

  const int npts   = in_sizes[0] / 16;
  const int ntiles = (npts + 31) / 32;   // per-point validity handled by npts masks? (N=2M -> exact)

  _Float16* W      = (_Float16*)d_ws;                          // 17*64*8 halfs
  float*    c2     = (float*)((char*)d_ws + (size_t)17*64*8*sizeof(_Float16));
  float*    partials = c2 + 32;

  const int GRID = 768, BLOCK = 256;   // 3 blocks/CU, one resident round
  setup_kernel<<<32, 64, 0, stream>>>(means, cov_parts, log_weights, W, c2);
  main_kernel<<<GRID, BLOCK, 0, stream>>>(data, W, c2, partials, npts, ntiles);
  reduce_kernel<<<1, 256, 0, stream>>>(partials, GRID, (float*)d_out,
                                       LN2_D / (2.0 * (double)npts));
}

// Round 5
// 212.868 us; speedup vs baseline: 1.2232x; 1.2232x over previous
//
#include <hip/hip_runtime.h>
#include <math.h>

// ---------------------------------------------------------------------------
// GMM log-likelihood, N=2M x D=16, K=32, out = mean_n logsumexp_k loglik[n,k]
//
// loglik[n,k] = sum_{ij} (-0.5 P_ij) x_i x_j + (P mu)_i x_i + c_k  (log2 dom.)
// LINEAR in phi(x) = [ x_i*x_j (256), x_i (16), 1 ] -> 18 K16-chunks of one
// chained mfma_f32_32x32x16_f16 (M=32 = all comps; c_k folded in as chunk 17
// so NO epilogue constant add and no 16-reg c2 array).
// C layout (HW-verified): col=lane&31 (point), row=(reg&3)+8*(reg>>2)+4*(lane>>5).
// Lane pair (l, l^32) holds all 32 comps of a point; combined via
// v_permlane32_swap (VALU-only; ds shuffles cost ~62 cyc each, R2).
//
// R5: R4 spilled ~27 dwords/iter to scratch (WRITE_SIZE 220 MB!) because the
// (256,3) unified VGPR budget splits 84 arch + 84 acc and live state was
// ~116 arch. Diet: x held as f16x2 (8 regs/tile), xi broadcast per chunk
// from element (op_sel), c2 folded into MFMA, single base pointer with
// offset:2048 for tile B. Target arch regs ~80 <= 84 -> zero scratch.
// ---------------------------------------------------------------------------

#define LOG_2PI 1.8378770664093453f
#define INV_LN2 1.4426950408889634f
#define LN2_D   0.6931471805599453

typedef float    float4v __attribute__((ext_vector_type(4)));
typedef float    f32x16  __attribute__((ext_vector_type(16)));
typedef _Float16 f16x8   __attribute__((ext_vector_type(8)));
typedef _Float16 f16x2   __attribute__((ext_vector_type(2)));

union H8 { f16x8 h8; f16x2 h2[4]; };

#if __has_builtin(__builtin_amdgcn_exp2f)
#define EXP2F(x) __builtin_amdgcn_exp2f(x)
#else
#define EXP2F(x) exp2f(x)
#endif
#if __has_builtin(__builtin_amdgcn_logf)
#define LOG2F(x) __builtin_amdgcn_logf(x)
#else
#define LOG2F(x) log2f(x)
#endif

static __device__ __forceinline__ f16x2 pk2(float a, float b) {
#if __has_builtin(__builtin_amdgcn_cvt_pkrtz)
  return __builtin_bit_cast(f16x2, __builtin_amdgcn_cvt_pkrtz(a, b));
#else
  f16x2 r; r[0] = (_Float16)a; r[1] = (_Float16)b; return r;
#endif
}

// value of x in partner lane (lane ^ 32), VALU-only on gfx950
static __device__ __forceinline__ float partner32(float x, bool lo) {
#if __has_builtin(__builtin_amdgcn_permlane32_swap)
  typedef unsigned u32x2 __attribute__((ext_vector_type(2)));
  unsigned u = __builtin_bit_cast(unsigned, x);
  u32x2 r = __builtin_amdgcn_permlane32_swap(u, u, false, false);
  return __builtin_bit_cast(float, lo ? r[1] : r[0]);
#else
  return __shfl_xor(x, 32, 64);
#endif
}

// dword select (works for f16x2 payloads)
static __device__ __forceinline__ f16x2 sel2(bool c, f16x2 a, f16x2 b) {
  unsigned ua = __builtin_bit_cast(unsigned, a);
  unsigned ub = __builtin_bit_cast(unsigned, b);
  return __builtin_bit_cast(f16x2, c ? ua : ub);
}

// ---------------------------------------------------------------------------
// Setup: per component k: cov = A A^T, Cholesky L, Linv, P = Linv^T Linv.
// W in 32x32x16 A-frag order: lane l holds A[m=l&31][k16 = 8*(l>>5)+v],
// chunk c covers feature k = 16c + 8h + v.
// chunks 0..15: (i,j)=(c, 8h+v) -> -0.5/ln2 * P[i][j]
// chunk 16: linear, feature i=8h+v -> (P mu)_i / ln2
// chunk 17: constant, slot (h=0,v=0) -> c2[m]; all other slots 0
// ---------------------------------------------------------------------------
__global__ void setup_kernel(const float* __restrict__ means,
                             const float* __restrict__ cov_parts,
                             const float* __restrict__ log_weights,
                             _Float16* __restrict__ W)
{
  const int k = blockIdx.x;
  const int i = threadIdx.x;

  __shared__ float sA[16][17];
  __shared__ float sC[16][17];
  __shared__ float sMu[16];
  __shared__ float sR[16];

  if (i < 16) {
    #pragma unroll
    for (int j = 0; j < 16; ++j) sA[i][j] = cov_parts[(k*16 + i)*16 + j];
    sMu[i] = means[k*16 + i];
  }
  __syncthreads();

  if (i < 16) {
    #pragma unroll
    for (int j = 0; j < 16; ++j) {
      float acc = 0.f;
      #pragma unroll
      for (int l = 0; l < 16; ++l) acc += sA[i][l] * sA[j][l];
      sC[i][j] = acc;
    }
  }
  __syncthreads();

  for (int j = 0; j < 16; ++j) {
    if (i == j) {
      float d = sC[j][j];
      for (int l = 0; l < j; ++l) d -= sC[j][l]*sC[j][l];
      sC[j][j] = sqrtf(d);
    }
    __syncthreads();
    if (i < 16 && i > j) {
      float a = sC[i][j];
      for (int l = 0; l < j; ++l) a -= sC[i][l]*sC[j][l];
      sC[i][j] = a / sC[j][j];
    }
    __syncthreads();
  }

  if (i < 16) {
    float y[16];
    #pragma unroll
    for (int r = 0; r < 16; ++r) {
      float a = (r == i) ? 1.f : 0.f;
      #pragma unroll
      for (int l = 0; l < r; ++l) a -= sC[r][l] * y[l];
      y[r] = a / sC[r][r];
    }
    #pragma unroll
    for (int r = 0; r < 16; ++r) sA[r][i] = y[r];
  }
  __syncthreads();

  if (i < 16) {
    float p[16];
    #pragma unroll
    for (int j = 0; j < 16; ++j) {
      float acc = 0.f;
      #pragma unroll
      for (int l = 0; l < 16; ++l) acc += sA[l][i] * sA[l][j];
      p[j] = acc;
    }
    float ri = 0.f;
    #pragma unroll
    for (int j = 0; j < 16; ++j) ri += p[j] * sMu[j];
    sR[i] = ri;

    #pragma unroll
    for (int j = 0; j < 16; ++j) {
      W[(size_t)(i*64 + (k + 32*(j >> 3)))*8 + (j & 7)] =
          (_Float16)(-0.5f * INV_LN2 * p[j]);
    }
    W[(size_t)(16*64 + (k + 32*(i >> 3)))*8 + (i & 7)] =
        (_Float16)(INV_LN2 * ri);
  }
  __syncthreads();

  if (i == 0) {
    float logdet = 0.f;
    #pragma unroll
    for (int j = 0; j < 16; ++j) logdet += __logf(sC[j][j]);
    float mupmu = 0.f;
    #pragma unroll
    for (int j = 0; j < 16; ++j) mupmu += sMu[j] * sR[j];
    float lw = log_weights[k];
    float c2v = INV_LN2 * (-0.5f*(mupmu + 16.f*LOG_2PI) - logdet + lw*lw);
    #pragma unroll
    for (int v = 0; v < 8; ++v) {
      W[(size_t)(17*64 + k)*8 + v]      = (v == 0) ? (_Float16)c2v : (_Float16)0.f;
      W[(size_t)(17*64 + k + 32)*8 + v] = (_Float16)0.f;
    }
  }
}

// ---------------------------------------------------------------------------
__global__ __launch_bounds__(256, 3) void main_kernel(
    const float* __restrict__ data,
    const _Float16* __restrict__ W,
    float* __restrict__ partials,
    int npairs)
{
  __shared__ _Float16 sW[18*64*8];     // 18432 B
  __shared__ float wsum[4];

  { // block-cooperative W copy (once)
    const float4v* src = (const float4v*)W;
    float4v* dst = (float4v*)sW;
    for (int idx = threadIdx.x; idx < 18*64*8/8; idx += 256)
      dst[idx] = src[idx];
  }
  __syncthreads();

  const int lane = threadIdx.x & 63;
  const int n32  = lane & 31;
  const bool lo  = lane < 32;
  const int gwave  = (int)((blockIdx.x * blockDim.x + threadIdx.x) >> 6);
  const int nwaves = (int)((gridDim.x * blockDim.x) >> 6);

  const _Float16* sWl = sW + (size_t)lane*8;   // chunk c at +c*512 halfs

  // constant B fragment for the c2 chunk: slot (h=0,v=0) = 1
  H8 bC;
  #pragma unroll
  for (int j = 0; j < 4; ++j) bC.h2[j] = pk2(0.f, 0.f);
  if (lo) bC.h2[0] = pk2(1.f, 0.f);

  float accsum = 0.f;

  // pair p covers points [p*64, p*64+64): tile A = +n32, tile B = +32+n32
  const char* ptr = (const char*)data + ((size_t)gwave*4096 + (size_t)n32*64);
  const size_t step = (size_t)nwaves * 4096;

  float4v pA0, pA1, pA2, pA3, pB0, pB1, pB2, pB3;
  if (gwave < npairs) {
    pA0 = *(const float4v*)(ptr);        pA1 = *(const float4v*)(ptr + 16);
    pA2 = *(const float4v*)(ptr + 32);   pA3 = *(const float4v*)(ptr + 48);
    pB0 = *(const float4v*)(ptr + 2048); pB1 = *(const float4v*)(ptr + 2064);
    pB2 = *(const float4v*)(ptr + 2080); pB3 = *(const float4v*)(ptr + 2096);
  }

  for (int p = gwave; p < npairs; p += nwaves) {
    // convert to f16 pairs: xh[t] = (x[2t], x[2t+1])
    f16x2 xhA[8], xhB[8];
    xhA[0] = pk2(pA0[0], pA0[1]); xhA[1] = pk2(pA0[2], pA0[3]);
    xhA[2] = pk2(pA1[0], pA1[1]); xhA[3] = pk2(pA1[2], pA1[3]);
    xhA[4] = pk2(pA2[0], pA2[1]); xhA[5] = pk2(pA2[2], pA2[3]);
    xhA[6] = pk2(pA3[0], pA3[1]); xhA[7] = pk2(pA3[2], pA3[3]);
    xhB[0] = pk2(pB0[0], pB0[1]); xhB[1] = pk2(pB0[2], pB0[3]);
    xhB[2] = pk2(pB1[0], pB1[1]); xhB[3] = pk2(pB1[2], pB1[3]);
    xhB[4] = pk2(pB2[0], pB2[1]); xhB[5] = pk2(pB2[2], pB2[3]);
    xhB[6] = pk2(pB3[0], pB3[1]); xhB[7] = pk2(pB3[2], pB3[3]);

    ptr += step;
    if (p + nwaves < npairs) {          // wave-uniform prefetch of next pair
      pA0 = *(const float4v*)(ptr);        pA1 = *(const float4v*)(ptr + 16);
      pA2 = *(const float4v*)(ptr + 32);   pA3 = *(const float4v*)(ptr + 48);
      pB0 = *(const float4v*)(ptr + 2048); pB1 = *(const float4v*)(ptr + 2064);
      pB2 = *(const float4v*)(ptr + 2080); pB3 = *(const float4v*)(ptr + 2096);
    }

    // second factors for this lane half: xsel[j] = xh[4h + j]
    f16x2 xsA[4], xsB[4];
    #pragma unroll
    for (int j = 0; j < 4; ++j) {
      xsA[j] = sel2(lo, xhA[j], xhA[4+j]);
      xsB[j] = sel2(lo, xhB[j], xhB[4+j]);
    }

    f32x16 accA, accB;
    #pragma unroll
    for (int r = 0; r < 16; ++r) { accA[r] = 0.f; accB[r] = 0.f; }

    #pragma unroll
    for (int c = 0; c < 16; ++c) {
      f16x8 wc = *(const f16x8*)(sWl + (size_t)c*512);   // ds_read_b128
      _Float16 xiA = xhA[c >> 1][c & 1];
      f16x2 xiA2; xiA2[0] = xiA; xiA2[1] = xiA;
      H8 bA;
      #pragma unroll
      for (int j = 0; j < 4; ++j) bA.h2[j] = xiA2 * xsA[j];
      accA = __builtin_amdgcn_mfma_f32_32x32x16_f16(wc, bA.h8, accA, 0, 0, 0);
      _Float16 xiB = xhB[c >> 1][c & 1];
      f16x2 xiB2; xiB2[0] = xiB; xiB2[1] = xiB;
      H8 bB;
      #pragma unroll
      for (int j = 0; j < 4; ++j) bB.h2[j] = xiB2 * xsB[j];
      accB = __builtin_amdgcn_mfma_f32_32x32x16_f16(wc, bB.h8, accB, 0, 0, 0);
    }
    {   // linear chunk
      f16x8 wc = *(const f16x8*)(sWl + (size_t)16*512);
      H8 bA, bB;
      #pragma unroll
      for (int j = 0; j < 4; ++j) { bA.h2[j] = xsA[j]; bB.h2[j] = xsB[j]; }
      accA = __builtin_amdgcn_mfma_f32_32x32x16_f16(wc, bA.h8, accA, 0, 0, 0);
      accB = __builtin_amdgcn_mfma_f32_32x32x16_f16(wc, bB.h8, accB, 0, 0, 0);
    }
    {   // c2 chunk
      f16x8 wc = *(const f16x8*)(sWl + (size_t)17*512);
      accA = __builtin_amdgcn_mfma_f32_32x32x16_f16(wc, bC.h8, accA, 0, 0, 0);
      accB = __builtin_amdgcn_mfma_f32_32x32x16_f16(wc, bC.h8, accB, 0, 0, 0);
    }

    // epilogue: logsumexp (log2 domain), acc already includes c2
    {
      float m = accA[0];
      #pragma unroll
      for (int r = 1; r < 16; ++r) m = fmaxf(m, accA[r]);
      m = fmaxf(m, partner32(m, lo));
      float s = 0.f;
      #pragma unroll
      for (int r = 0; r < 16; ++r) s += EXP2F(accA[r] - m);
      s += partner32(s, lo);
      accsum += m + LOG2F(s);
    }
    {
      float m = accB[0];
      #pragma unroll
      for (int r = 1; r < 16; ++r) m = fmaxf(m, accB[r]);
      m = fmaxf(m, partner32(m, lo));
      float s = 0.f;
      #pragma unroll
      for (int r = 0; r < 16; ++r) s += EXP2F(accB[r] - m);
      s += partner32(s, lo);
      accsum += m + LOG2F(s);
    }
  }

  #pragma unroll
  for (int off = 1; off <= 32; off <<= 1)
    accsum += __shfl_xor(accsum, off, 64);

  const int wid = (int)(threadIdx.x >> 6);
  if ((threadIdx.x & 63) == 0) wsum[wid] = accsum;
  __syncthreads();
  if (threadIdx.x == 0)
    partials[blockIdx.x] = wsum[0] + wsum[1] + wsum[2] + wsum[3];
}

// ---------------------------------------------------------------------------
__global__ void reduce_kernel(const float* __restrict__ partials, int n,
                              float* __restrict__ out, double scale)
{
  __shared__ double sd[256];
  double a = 0.0;
  for (int idx = threadIdx.x; idx < n; idx += 256) a += (double)partials[idx];
  sd[threadIdx.x] = a;
  __syncthreads();
  for (int s = 128; s > 0; s >>= 1) {
    if ((int)threadIdx.x < s) sd[threadIdx.x] += sd[threadIdx.x + s];
    __syncthreads();
  }
  if (threadIdx.x == 0) out[0] = (float)(sd[0] * scale);
}

extern "C" void kernel_launch(void* const* d_in, const int* in_sizes, int n_in,
                              void* d_out, int out_size, void* d_ws, size_t ws_size,
                              hipStream_t stream)
{
  const float* data        = (const float*)d_in[0];
  const float* means       = (const float*)d_in[1];
  const float* cov_parts   = (const float*)d_in[2];
  const float* log_weights = (const float*)d_in[3];

  const int npts   = in_sizes[0] / 16;
  const int npairs = npts / 64;        // N = 2,000,000 divisible by 64

  _Float16* W      = (_Float16*)d_ws;                          // 18*64*8 halfs
  float*    partials = (float*)((char*)d_ws + (size_t)18*64*8*sizeof(_Float16));

  const int GRID = 768, BLOCK = 256;   // 3 blocks/CU, one resident round
  setup_kernel<<<32, 64, 0, stream>>>(means, cov_parts, log_weights, W);
  main_kernel<<<GRID, BLOCK, 0, stream>>>(data, W, partials, npairs);
  reduce_kernel<<<1, 256, 0, stream>>>(partials, GRID, (float*)d_out,
                                       LN2_D / (2.0 * (double)npts));
}

// Round 6
// 202.949 us; speedup vs baseline: 1.2830x; 1.0489x over previous
//
#include <hip/hip_runtime.h>
#include <math.h>

// ---------------------------------------------------------------------------
// GMM log-likelihood, N=2M x D=16, K=32, out = mean_n logsumexp_k loglik[n,k]
//
// loglik[n,k] = sum_{ij} (-0.5 P_ij) x_i x_j + (P mu)_i x_i + c_k  (log2 dom.)
// LINEAR in phi(x) = [ x_i*x_j (256), x_i (16), 1 ] -> 18 K16-chunks of one
// chained mfma_f32_32x32x16_f16 (M=32 = all comps; c_k folded in as chunk 17).
// C layout (HW-verified): col=lane&31 (point), row=(reg&3)+8*(reg>>2)+4*(lane>>5).
// Lane pair (l, l^32) holds all 32 comps of a point; combined via
// v_permlane32_swap (VALU-only; ds shuffles cost ~62 cyc each, R2).
//
// R6: R5's W-in-LDS costs 36 ds_read_b128/pair-iter = ~22 us/CU of LDS issue
// (1.125M b128 reads / 256 CU x 12cyc) stacked on the 21 us HBM floor.
// Fix: W resident in REGISTERS (gfx950 unified VGPR/AGPR file).
// __launch_bounds__(256,2) -> 256 regs/wave: W 72 + acc 32 + prefetch 32 +
// xh/xs 24 + misc ~20 = ~180, fits with headroom -> no spill (R4 lesson:
// WRITE_SIZE is the spill tell), no LDS in the loop at all.
// Grid 512 = exactly 2 blocks/CU, persistent waves.
// ---------------------------------------------------------------------------

#define LOG_2PI 1.8378770664093453f
#define INV_LN2 1.4426950408889634f
#define LN2_D   0.6931471805599453

typedef float    float4v __attribute__((ext_vector_type(4)));
typedef float    f32x16  __attribute__((ext_vector_type(16)));
typedef _Float16 f16x8   __attribute__((ext_vector_type(8)));
typedef _Float16 f16x2   __attribute__((ext_vector_type(2)));

union H8 { f16x8 h8; f16x2 h2[4]; };

#if __has_builtin(__builtin_amdgcn_exp2f)
#define EXP2F(x) __builtin_amdgcn_exp2f(x)
#else
#define EXP2F(x) exp2f(x)
#endif
#if __has_builtin(__builtin_amdgcn_logf)
#define LOG2F(x) __builtin_amdgcn_logf(x)
#else
#define LOG2F(x) log2f(x)
#endif

static __device__ __forceinline__ f16x2 pk2(float a, float b) {
#if __has_builtin(__builtin_amdgcn_cvt_pkrtz)
  return __builtin_bit_cast(f16x2, __builtin_amdgcn_cvt_pkrtz(a, b));
#else
  f16x2 r; r[0] = (_Float16)a; r[1] = (_Float16)b; return r;
#endif
}

// value of x in partner lane (lane ^ 32), VALU-only on gfx950
static __device__ __forceinline__ float partner32(float x, bool lo) {
#if __has_builtin(__builtin_amdgcn_permlane32_swap)
  typedef unsigned u32x2 __attribute__((ext_vector_type(2)));
  unsigned u = __builtin_bit_cast(unsigned, x);
  u32x2 r = __builtin_amdgcn_permlane32_swap(u, u, false, false);
  return __builtin_bit_cast(float, lo ? r[1] : r[0]);
#else
  return __shfl_xor(x, 32, 64);
#endif
}

// dword select (works for f16x2 payloads)
static __device__ __forceinline__ f16x2 sel2(bool c, f16x2 a, f16x2 b) {
  unsigned ua = __builtin_bit_cast(unsigned, a);
  unsigned ub = __builtin_bit_cast(unsigned, b);
  return __builtin_bit_cast(f16x2, c ? ua : ub);
}

// ---------------------------------------------------------------------------
// Setup: per component k: cov = A A^T, Cholesky L, Linv, P = Linv^T Linv.
// W in 32x32x16 A-frag order: lane l holds A[m=l&31][k16 = 8*(l>>5)+v],
// chunk c covers feature k = 16c + 8h + v.
// chunks 0..15: (i,j)=(c, 8h+v) -> -0.5/ln2 * P[i][j]
// chunk 16: linear, feature i=8h+v -> (P mu)_i / ln2
// chunk 17: constant, slot (h=0,v=0) -> c2[m]; all other slots 0
// ---------------------------------------------------------------------------
__global__ void setup_kernel(const float* __restrict__ means,
                             const float* __restrict__ cov_parts,
                             const float* __restrict__ log_weights,
                             _Float16* __restrict__ W)
{
  const int k = blockIdx.x;
  const int i = threadIdx.x;

  __shared__ float sA[16][17];
  __shared__ float sC[16][17];
  __shared__ float sMu[16];
  __shared__ float sR[16];

  if (i < 16) {
    #pragma unroll
    for (int j = 0; j < 16; ++j) sA[i][j] = cov_parts[(k*16 + i)*16 + j];
    sMu[i] = means[k*16 + i];
  }
  __syncthreads();

  if (i < 16) {
    #pragma unroll
    for (int j = 0; j < 16; ++j) {
      float acc = 0.f;
      #pragma unroll
      for (int l = 0; l < 16; ++l) acc += sA[i][l] * sA[j][l];
      sC[i][j] = acc;
    }
  }
  __syncthreads();

  for (int j = 0; j < 16; ++j) {
    if (i == j) {
      float d = sC[j][j];
      for (int l = 0; l < j; ++l) d -= sC[j][l]*sC[j][l];
      sC[j][j] = sqrtf(d);
    }
    __syncthreads();
    if (i < 16 && i > j) {
      float a = sC[i][j];
      for (int l = 0; l < j; ++l) a -= sC[i][l]*sC[j][l];
      sC[i][j] = a / sC[j][j];
    }
    __syncthreads();
  }

  if (i < 16) {
    float y[16];
    #pragma unroll
    for (int r = 0; r < 16; ++r) {
      float a = (r == i) ? 1.f : 0.f;
      #pragma unroll
      for (int l = 0; l < r; ++l) a -= sC[r][l] * y[l];
      y[r] = a / sC[r][r];
    }
    #pragma unroll
    for (int r = 0; r < 16; ++r) sA[r][i] = y[r];
  }
  __syncthreads();

  if (i < 16) {
    float p[16];
    #pragma unroll
    for (int j = 0; j < 16; ++j) {
      float acc = 0.f;
      #pragma unroll
      for (int l = 0; l < 16; ++l) acc += sA[l][i] * sA[l][j];
      p[j] = acc;
    }
    float ri = 0.f;
    #pragma unroll
    for (int j = 0; j < 16; ++j) ri += p[j] * sMu[j];
    sR[i] = ri;

    #pragma unroll
    for (int j = 0; j < 16; ++j) {
      W[(size_t)(i*64 + (k + 32*(j >> 3)))*8 + (j & 7)] =
          (_Float16)(-0.5f * INV_LN2 * p[j]);
    }
    W[(size_t)(16*64 + (k + 32*(i >> 3)))*8 + (i & 7)] =
        (_Float16)(INV_LN2 * ri);
  }
  __syncthreads();

  if (i == 0) {
    float logdet = 0.f;
    #pragma unroll
    for (int j = 0; j < 16; ++j) logdet += __logf(sC[j][j]);
    float mupmu = 0.f;
    #pragma unroll
    for (int j = 0; j < 16; ++j) mupmu += sMu[j] * sR[j];
    float lw = log_weights[k];
    float c2v = INV_LN2 * (-0.5f*(mupmu + 16.f*LOG_2PI) - logdet + lw*lw);
    #pragma unroll
    for (int v = 0; v < 8; ++v) {
      W[(size_t)(17*64 + k)*8 + v]      = (v == 0) ? (_Float16)c2v : (_Float16)0.f;
      W[(size_t)(17*64 + k + 32)*8 + v] = (_Float16)0.f;
    }
  }
}

// ---------------------------------------------------------------------------
__global__ __launch_bounds__(256, 2) void main_kernel(
    const float* __restrict__ data,
    const _Float16* __restrict__ W,
    float* __restrict__ partials,
    int npairs)
{
  const int lane = threadIdx.x & 63;
  const int n32  = lane & 31;
  const bool lo  = lane < 32;
  const int gwave  = (int)((blockIdx.x * blockDim.x + threadIdx.x) >> 6);
  const int nwaves = (int)((gridDim.x * blockDim.x) >> 6);

  // W fragments resident in registers for the whole kernel (72 regs)
  f16x8 Wf[18];
  #pragma unroll
  for (int c = 0; c < 18; ++c)
    Wf[c] = *(const f16x8*)(W + (size_t)(c*64 + lane)*8);

  // constant B fragment for the c2 chunk: slot (h=0,v=0) = 1
  H8 bC;
  #pragma unroll
  for (int j = 0; j < 4; ++j) bC.h2[j] = pk2(0.f, 0.f);
  if (lo) bC.h2[0] = pk2(1.f, 0.f);

  float accsum = 0.f;

  // pair p covers points [p*64, p*64+64): tile A = +n32, tile B = +32+n32
  const char* ptr = (const char*)data + ((size_t)gwave*4096 + (size_t)n32*64);
  const size_t step = (size_t)nwaves * 4096;

  float4v pA0, pA1, pA2, pA3, pB0, pB1, pB2, pB3;
  if (gwave < npairs) {
    pA0 = *(const float4v*)(ptr);        pA1 = *(const float4v*)(ptr + 16);
    pA2 = *(const float4v*)(ptr + 32);   pA3 = *(const float4v*)(ptr + 48);
    pB0 = *(const float4v*)(ptr + 2048); pB1 = *(const float4v*)(ptr + 2064);
    pB2 = *(const float4v*)(ptr + 2080); pB3 = *(const float4v*)(ptr + 2096);
  }

  for (int p = gwave; p < npairs; p += nwaves) {
    // convert to f16 pairs: xh[t] = (x[2t], x[2t+1])
    f16x2 xhA[8], xhB[8];
    xhA[0] = pk2(pA0[0], pA0[1]); xhA[1] = pk2(pA0[2], pA0[3]);
    xhA[2] = pk2(pA1[0], pA1[1]); xhA[3] = pk2(pA1[2], pA1[3]);
    xhA[4] = pk2(pA2[0], pA2[1]); xhA[5] = pk2(pA2[2], pA2[3]);
    xhA[6] = pk2(pA3[0], pA3[1]); xhA[7] = pk2(pA3[2], pA3[3]);
    xhB[0] = pk2(pB0[0], pB0[1]); xhB[1] = pk2(pB0[2], pB0[3]);
    xhB[2] = pk2(pB1[0], pB1[1]); xhB[3] = pk2(pB1[2], pB1[3]);
    xhB[4] = pk2(pB2[0], pB2[1]); xhB[5] = pk2(pB2[2], pB2[3]);
    xhB[6] = pk2(pB3[0], pB3[1]); xhB[7] = pk2(pB3[2], pB3[3]);

    ptr += step;
    if (p + nwaves < npairs) {          // wave-uniform prefetch of next pair
      pA0 = *(const float4v*)(ptr);        pA1 = *(const float4v*)(ptr + 16);
      pA2 = *(const float4v*)(ptr + 32);   pA3 = *(const float4v*)(ptr + 48);
      pB0 = *(const float4v*)(ptr + 2048); pB1 = *(const float4v*)(ptr + 2064);
      pB2 = *(const float4v*)(ptr + 2080); pB3 = *(const float4v*)(ptr + 2096);
    }

    // second factors for this lane half: xsel[j] = xh[4h + j]
    f16x2 xsA[4], xsB[4];
    #pragma unroll
    for (int j = 0; j < 4; ++j) {
      xsA[j] = sel2(lo, xhA[j], xhA[4+j]);
      xsB[j] = sel2(lo, xhB[j], xhB[4+j]);
    }

    f32x16 accA, accB;
    #pragma unroll
    for (int r = 0; r < 16; ++r) { accA[r] = 0.f; accB[r] = 0.f; }

    #pragma unroll
    for (int c = 0; c < 16; ++c) {
      _Float16 xiA = xhA[c >> 1][c & 1];
      H8 bA;
      #pragma unroll
      for (int j = 0; j < 4; ++j) bA.h2[j] = xsA[j] * xiA;  // v_pk_mul_f16
      accA = __builtin_amdgcn_mfma_f32_32x32x16_f16(Wf[c], bA.h8, accA, 0, 0, 0);
      _Float16 xiB = xhB[c >> 1][c & 1];
      H8 bB;
      #pragma unroll
      for (int j = 0; j < 4; ++j) bB.h2[j] = xsB[j] * xiB;
      accB = __builtin_amdgcn_mfma_f32_32x32x16_f16(Wf[c], bB.h8, accB, 0, 0, 0);
    }
    {   // linear chunk
      H8 bA, bB;
      #pragma unroll
      for (int j = 0; j < 4; ++j) { bA.h2[j] = xsA[j]; bB.h2[j] = xsB[j]; }
      accA = __builtin_amdgcn_mfma_f32_32x32x16_f16(Wf[16], bA.h8, accA, 0, 0, 0);
      accB = __builtin_amdgcn_mfma_f32_32x32x16_f16(Wf[16], bB.h8, accB, 0, 0, 0);
    }
    {   // c2 chunk
      accA = __builtin_amdgcn_mfma_f32_32x32x16_f16(Wf[17], bC.h8, accA, 0, 0, 0);
      accB = __builtin_amdgcn_mfma_f32_32x32x16_f16(Wf[17], bC.h8, accB, 0, 0, 0);
    }

    // epilogue: logsumexp (log2 domain), acc already includes c2
    {
      float m = accA[0];
      #pragma unroll
      for (int r = 1; r < 16; ++r) m = fmaxf(m, accA[r]);
      m = fmaxf(m, partner32(m, lo));
      float s = 0.f;
      #pragma unroll
      for (int r = 0; r < 16; ++r) s += EXP2F(accA[r] - m);
      s += partner32(s, lo);
      accsum += m + LOG2F(s);
    }
    {
      float m = accB[0];
      #pragma unroll
      for (int r = 1; r < 16; ++r) m = fmaxf(m, accB[r]);
      m = fmaxf(m, partner32(m, lo));
      float s = 0.f;
      #pragma unroll
      for (int r = 0; r < 16; ++r) s += EXP2F(accB[r] - m);
      s += partner32(s, lo);
      accsum += m + LOG2F(s);
    }
  }

  #pragma unroll
  for (int off = 1; off <= 32; off <<= 1)
    accsum += __shfl_xor(accsum, off, 64);

  __shared__ float wsum[4];
  const int wid = (int)(threadIdx.x >> 6);
  if ((threadIdx.x & 63) == 0) wsum[wid] = accsum;
  __syncthreads();
  if (threadIdx.x == 0)
    partials[blockIdx.x] = wsum[0] + wsum[1] + wsum[2] + wsum[3];
}

// ---------------------------------------------------------------------------
__global__ void reduce_kernel(const float* __restrict__ partials, int n,
                              float* __restrict__ out, double scale)
{
  __shared__ double sd[256];
  double a = 0.0;
  for (int idx = threadIdx.x; idx < n; idx += 256) a += (double)partials[idx];
  sd[threadIdx.x] = a;
  __syncthreads();
  for (int s = 128; s > 0; s >>= 1) {
    if ((int)threadIdx.x < s) sd[threadIdx.x] += sd[threadIdx.x + s];
    __syncthreads();
  }
  if (threadIdx.x == 0) out[0] = (float)(sd[0] * scale);
}

extern "C" void kernel_launch(void* const* d_in, const int* in_sizes, int n_in,
                              void* d_out, int out_size, void* d_ws, size_t ws_size,
                              hipStream_t stream)
{
  const float* data        = (const float*)d_in[0];
  const float* means       = (const float*)d_in[1];
  const float* cov_parts   = (const float*)d_in[2];
  const float* log_weights = (const float*)d_in[3];

  const int npts   = in_sizes[0] / 16;
  const int npairs = npts / 64;        // N = 2,000,000 divisible by 64

  _Float16* W      = (_Float16*)d_ws;                          // 18*64*8 halfs
  float*    partials = (float*)((char*)d_ws + (size_t)18*64*8*sizeof(_Float16));

  const int GRID = 512, BLOCK = 256;   // 2 blocks/CU, one resident round
  setup_kernel<<<32, 64, 0, stream>>>(means, cov_parts, log_weights, W);
  main_kernel<<<GRID, BLOCK, 0, stream>>>(data, W, partials, npairs);
  reduce_kernel<<<1, 256, 0, stream>>>(partials, GRID, (float*)d_out,
                                       LN2_D / (2.0 * (double)npts));
}